// Round 1
// baseline (4009.200 us; speedup 1.0000x reference)
//
#include <hip/hip_runtime.h>

// Problem constants
//  L=4, MM=2, C=128, H=64, OUTC=128, EDGE_CH=128, X_EDGE=384, C3=384
//  NRED=19, NFULL=25, E=10000, N_NODES=1000
//  mp row = 19*384 = 7296 floats; effective w_m0 rows 512..1087 (576 outs)

__constant__ int c_MASKP[19] = {0,2,6,12,20, 3,7,13,21, 1,5,11,19, 8,14,22, 4,10,18};
__constant__ int c_GATEP[19] = {-1,0,1,2,3, 0,1,2,3, 0,1,2,3, 1,2,3, 1,2,3};
__constant__ int c_LFULL[25] = {0,1,1,1,2,2,2,2,2,3,3,3,3,3,3,3,4,4,4,4,4,4,4,4,4};

__device__ __forceinline__ float sigm_(float x) { return 1.f / (1.f + __expf(-x)); }

// ---------------------------------------------------------------------------
// K0: transpose proj_w (5,128,64) -> pwT (5,64,128): pwT[l][i][o] = pw[l][o][i]
__global__ void k_transpose_pw(const float* __restrict__ pw, float* __restrict__ pwT) {
    int d = blockIdx.x * 256 + threadIdx.x;
    if (d >= 40960) return;
    int l = d >> 13, rem = d & 8191, i = rem >> 7, o = rem & 127;
    pwT[d] = pw[(l << 13) + o * 64 + i];
}

// ---------------------------------------------------------------------------
// K1: per 8 edges: x_edge = [edge_distance | src_emb | tgt_emb] (384)
//     h1 = silu(LN(x_edge @ w1^T + b1)); h2 = silu(LN(h1 @ w2^T + b2))
__global__ __launch_bounds__(256) void k_radial_front(
    const float* __restrict__ ed, const float* __restrict__ se, const float* __restrict__ te,
    const float* __restrict__ w1, const float* __restrict__ b1,
    const float* __restrict__ g1, const float* __restrict__ bb1,
    const float* __restrict__ w2, const float* __restrict__ b2,
    const float* __restrict__ g2, const float* __restrict__ bb2,
    const int* __restrict__ an, const int* __restrict__ eidx,
    float* __restrict__ h2out, int e0, int ec, int E)
{
    __shared__ float xe[8 * 384];
    __shared__ float hb[8 * 128];
    __shared__ float hb2[8 * 128];
    __shared__ float stats[8][2];
    int tid = threadIdx.x;
    int ebase = e0 + blockIdx.x * 8;
    int elim = e0 + ec;

    for (int idx = tid; idx < 8 * 384; idx += 256) {
        int es = idx / 384, c = idx - es * 384;
        int e = ebase + es;
        float v = 0.f;
        if (e < elim) {
            if (c < 128)       v = ed[(long)e * 128 + c];
            else if (c < 256)  { int s = eidx[e];     v = se[an[s] * 128 + (c - 128)]; }
            else               { int t = eidx[E + e]; v = te[an[t] * 128 + (c - 256)]; }
        }
        xe[idx] = v;
    }
    __syncthreads();

    int o = tid & 127;
    int half = tid >> 7;
    // GEMM1: 8x128, K=384
    for (int pass = 0; pass < 4; ++pass) {
        int es = pass * 2 + half;
        float acc = b1[o];
        const float4* wr = (const float4*)(w1 + (long)o * 384);
        const float4* xr = (const float4*)(xe + es * 384);
        #pragma unroll 8
        for (int k = 0; k < 96; ++k) {
            float4 w = wr[k], xv = xr[k];
            acc += w.x * xv.x + w.y * xv.y + w.z * xv.z + w.w * xv.w;
        }
        hb[es * 128 + o] = acc;
    }
    __syncthreads();
    if (tid < 8) {
        float s = 0.f, s2 = 0.f;
        for (int k = 0; k < 128; ++k) { float v = hb[tid * 128 + k]; s += v; s2 += v * v; }
        float mu = s * (1.f / 128.f);
        float var = s2 * (1.f / 128.f) - mu * mu;
        stats[tid][0] = mu;
        stats[tid][1] = rsqrtf(var + 1e-5f);
    }
    __syncthreads();
    for (int idx = tid; idx < 1024; idx += 256) {
        int es = idx >> 7, c = idx & 127;
        float v = (hb[idx] - stats[es][0]) * stats[es][1] * g1[c] + bb1[c];
        hb[idx] = v * sigm_(v);
    }
    __syncthreads();
    // GEMM2: 8x128, K=128
    for (int pass = 0; pass < 4; ++pass) {
        int es = pass * 2 + half;
        float acc = b2[o];
        const float4* wr = (const float4*)(w2 + (long)o * 128);
        const float4* xr = (const float4*)(hb + es * 128);
        #pragma unroll 8
        for (int k = 0; k < 32; ++k) {
            float4 w = wr[k], xv = xr[k];
            acc += w.x * xv.x + w.y * xv.y + w.z * xv.z + w.w * xv.w;
        }
        hb2[es * 128 + o] = acc;
    }
    __syncthreads();
    if (tid < 8) {
        float s = 0.f, s2 = 0.f;
        for (int k = 0; k < 128; ++k) { float v = hb2[tid * 128 + k]; s += v; s2 += v * v; }
        float mu = s * (1.f / 128.f);
        float var = s2 * (1.f / 128.f) - mu * mu;
        stats[tid][0] = mu;
        stats[tid][1] = rsqrtf(var + 1e-5f);
    }
    __syncthreads();
    for (int idx = tid; idx < 1024; idx += 256) {
        int es = idx >> 7, c = idx & 127;
        int e = ebase + es;
        if (e < elim) {
            float v = (hb2[idx] - stats[es][0]) * stats[es][1] * g2[c] + bb2[c];
            v = v * sigm_(v);
            h2out[(long)(e - e0) * 128 + c] = v;
        }
    }
}

// ---------------------------------------------------------------------------
// Generic tiled fp32 GEMM: Out[r][o] = sum_k A(r)[k] * W[wRowOff+o][k] + bias
//   A(r) = Abase + (r/parts)*aEdgeStride + aOff + (r%parts)*aPartLen
#define GT_BK 32
__global__ __launch_bounds__(256) void k_gemm(
    const float* __restrict__ Abase, int aEdgeStride, int aOff, int aPartLen, int parts,
    const float* __restrict__ W, const float* __restrict__ bias, int wRowOff,
    float* __restrict__ Out, int ldo, int nRows, int N, int K)
{
    __shared__ float As[GT_BK][65];
    __shared__ float Bs[GT_BK][65];
    int r0 = blockIdx.x * 64, o0 = blockIdx.y * 64;
    int tx = threadIdx.x & 15, ty = threadIdx.x >> 4;
    float acc[4][4] = {};
    for (int kk = 0; kk < K; kk += GT_BK) {
        for (int i = threadIdx.x; i < 64 * GT_BK; i += 256) {
            int row = i >> 5, k = i & 31;
            int r = r0 + row;
            float v = 0.f;
            if (r < nRows) {
                int e = r / parts, p = r - e * parts;
                v = Abase[(long)e * aEdgeStride + aOff + (long)p * aPartLen + kk + k];
            }
            As[k][row] = v;
        }
        for (int i = threadIdx.x; i < 64 * GT_BK; i += 256) {
            int col = i >> 5, k = i & 31;
            int oo = o0 + col;
            float v = 0.f;
            if (oo < N) v = W[(long)(wRowOff + oo) * K + kk + k];
            Bs[k][col] = v;
        }
        __syncthreads();
        #pragma unroll
        for (int k = 0; k < GT_BK; ++k) {
            float a[4], b[4];
            #pragma unroll
            for (int i = 0; i < 4; ++i) a[i] = As[k][ty * 4 + i];
            #pragma unroll
            for (int j = 0; j < 4; ++j) b[j] = Bs[k][tx * 4 + j];
            #pragma unroll
            for (int i = 0; i < 4; ++i)
                #pragma unroll
                for (int j = 0; j < 4; ++j) acc[i][j] += a[i] * b[j];
        }
        __syncthreads();
    }
    #pragma unroll
    for (int i = 0; i < 4; ++i) {
        int r = r0 + ty * 4 + i;
        if (r >= nRows) continue;
        #pragma unroll
        for (int j = 0; j < 4; ++j) {
            int oo = o0 + tx * 4 + j;
            if (oo < N)
                Out[(long)r * ldo + oo] = acc[i][j] + (bias ? bias[wRowOff + oo] : 0.f);
        }
    }
}

// ---------------------------------------------------------------------------
// K3: per edge: msg[n][c] (gathered, scaled by w_rad[l(n)][c]); then
//     mp[j][c] = sum_n wig[MASKP[j]][n] * msg[n][c]   (already PERM_M order)
__global__ __launch_bounds__(384) void k_build_mp(
    const float* __restrict__ x, const float* __restrict__ ef, const float* __restrict__ wgn,
    const float* __restrict__ wrad, const int* __restrict__ eidx,
    float* __restrict__ mp, int e0, int E)
{
    __shared__ float swig[625];
    __shared__ float srad[1920];
    __shared__ float smsg[9600];
    int tid = threadIdx.x;
    int le = blockIdx.x;
    long e = e0 + le;
    int src = eidx[e], tgt = eidx[E + e];

    for (int i = tid; i < 625; i += 384)  swig[i] = wgn[e * 625 + i];
    for (int i = tid; i < 1920; i += 384) srad[i] = wrad[(long)le * 1920 + i];
    __syncthreads();
    int c = tid;  // 0..383
    for (int n = 0; n < 25; ++n) {
        float v;
        if (c < 128)      v = x[(long)src * 3200 + n * 128 + c];
        else if (c < 256) v = x[(long)tgt * 3200 + n * 128 + (c - 128)];
        else              v = ef[e * 3200 + n * 128 + (c - 256)];
        smsg[n * 384 + c] = v * srad[c_LFULL[n] * 384 + c];
    }
    __syncthreads();
    for (int j = 0; j < 19; ++j) {
        const float* wrow = swig + c_MASKP[j] * 25;
        float acc = 0.f;
        #pragma unroll
        for (int n = 0; n < 25; ++n) acc += wrow[n] * smsg[n * 384 + c];
        mp[(long)le * 7296 + j * 384 + c] = acc;
    }
}

// ---------------------------------------------------------------------------
// K5: per edge: assemble hl (perm order) w/ complex recombination + gating,
//     full[n][c] = sum_j wig[MASKP[j]][n]*hl[j][c], out = proj + bias on n=0
__global__ __launch_bounds__(256) void k_combine(
    const float* __restrict__ wgn, const float* __restrict__ ym0,
    const float* __restrict__ ym1, const float* __restrict__ ym2,
    const float* __restrict__ pwT, const float* __restrict__ pb,
    float* __restrict__ out, int e0)
{
    __shared__ float swig[625];
    __shared__ float shl[1216];   // 19 x 64
    __shared__ float sful[1600];  // 25 x 64
    __shared__ float spw[8192];   // 64 x 128 (one l at a time)
    int tid = threadIdx.x;
    int le = blockIdx.x;
    long e = e0 + le;

    for (int i = tid; i < 625; i += 256) swig[i] = wgn[e * 625 + i];

    const float* y0  = ym0 + (long)le * 576;
    const float* y1a = ym1 + (long)(2 * le) * 512;
    const float* y1b = ym1 + (long)(2 * le + 1) * 512;
    const float* y2a = ym2 + (long)(2 * le) * 384;
    const float* y2b = ym2 + (long)(2 * le + 1) * 384;

    for (int i = tid; i < 1216; i += 256) {
        int j = i >> 6, c = i & 63;
        float raw;
        if (j < 5)        raw = y0[256 + j * 64 + c];
        else if (j < 9)   { int k = (j - 5) * 64 + c;  raw = y1a[k] - y1b[256 + k]; }
        else if (j < 13)  { int k = (j - 9) * 64 + c;  raw = y1b[k] + y1a[256 + k]; }
        else if (j < 16)  { int k = (j - 13) * 64 + c; raw = y2a[k] - y2b[192 + k]; }
        else              { int k = (j - 16) * 64 + c; raw = y2b[k] + y2a[192 + k]; }
        float v;
        if (j == 0) v = raw * sigm_(raw);                          // silu on (l=0,m=0)
        else        v = raw * sigm_(y0[c_GATEP[j] * 64 + c]);      // gate
        shl[i] = v;
    }
    __syncthreads();
    for (int i = tid; i < 1600; i += 256) {
        int n = i >> 6, c = i & 63;
        float acc = 0.f;
        #pragma unroll
        for (int j = 0; j < 19; ++j) acc += swig[c_MASKP[j] * 25 + n] * shl[j * 64 + c];
        sful[i] = acc;
    }

    int o = tid & 127, sub = tid >> 7;
    for (int l = 0; l < 5; ++l) {
        __syncthreads();
        for (int i = tid; i < 8192; i += 256) spw[i] = pwT[l * 8192 + i];
        __syncthreads();
        int cnt = 2 * l + 1, nb = l * l;
        for (int ni = sub; ni < cnt; ni += 2) {
            int n = nb + ni;
            float acc = (n == 0) ? pb[o] : 0.f;
            const float* f = sful + n * 64;
            #pragma unroll 16
            for (int i = 0; i < 64; ++i) acc += f[i] * spw[i * 128 + o];
            out[e * 3200 + n * 128 + o] = acc;
        }
    }
}

// ---------------------------------------------------------------------------
extern "C" void kernel_launch(void* const* d_in, const int* in_sizes, int n_in,
                              void* d_out, int out_size, void* d_ws, size_t ws_size,
                              hipStream_t stream)
{
    const float* x    = (const float*)d_in[0];
    const float* ef   = (const float*)d_in[1];
    const float* ed   = (const float*)d_in[2];
    const float* wgn  = (const float*)d_in[3];
    const float* se   = (const float*)d_in[4];
    const float* te   = (const float*)d_in[5];
    const float* w1   = (const float*)d_in[6];
    const float* b1   = (const float*)d_in[7];
    const float* g1   = (const float*)d_in[8];
    const float* bb1  = (const float*)d_in[9];
    const float* w2   = (const float*)d_in[10];
    const float* b2   = (const float*)d_in[11];
    const float* g2   = (const float*)d_in[12];
    const float* bb2  = (const float*)d_in[13];
    const float* w3   = (const float*)d_in[14];
    const float* b3   = (const float*)d_in[15];
    const float* wm0  = (const float*)d_in[16];
    const float* bm0  = (const float*)d_in[17];
    const float* wm1  = (const float*)d_in[18];
    const float* wm2  = (const float*)d_in[19];
    const float* pw   = (const float*)d_in[20];
    const float* pb   = (const float*)d_in[21];
    const int*   an   = (const int*)d_in[22];
    const int*   eidx = (const int*)d_in[23];
    float* out = (float*)d_out;
    float* ws  = (float*)d_ws;

    const int E = in_sizes[23] / 2;           // 10000
    const long perEdge = 128 + 1920 + 7296 + 576 + 1024 + 768;  // 11712 floats
    long wsFloats = (long)(ws_size / 4);
    long avail = wsFloats - 40960 - 64;
    long ceL = avail / perEdge;
    int CE = (int)(ceL < (long)E ? ceL : (long)E);
    if (CE < 1) CE = 1;

    float* pwT  = ws;
    float* h2   = pwT + 40960;
    float* wrad = h2  + (long)CE * 128;
    float* mp   = wrad + (long)CE * 1920;
    float* y0   = mp  + (long)CE * 7296;
    float* y1   = y0  + (long)CE * 576;
    float* y2   = y1  + (long)CE * 1024;

    k_transpose_pw<<<160, 256, 0, stream>>>(pw, pwT);

    for (int e0 = 0; e0 < E; e0 += CE) {
        int ec = (E - e0 < CE) ? (E - e0) : CE;

        k_radial_front<<<dim3((ec + 7) / 8), 256, 0, stream>>>(
            ed, se, te, w1, b1, g1, bb1, w2, b2, g2, bb2, an, eidx, h2, e0, ec, E);

        dim3 gw3((ec + 63) / 64, 30);
        k_gemm<<<gw3, 256, 0, stream>>>(h2, 128, 0, 0, 1,
                                        w3, b3, 0, wrad, 1920, ec, 1920, 128);

        k_build_mp<<<dim3(ec), 384, 0, stream>>>(x, ef, wgn, wrad, eidx, mp, e0, E);

        dim3 g0((ec + 63) / 64, 9);
        k_gemm<<<g0, 256, 0, stream>>>(mp, 7296, 0, 0, 1,
                                       wm0, bm0, 512, y0, 576, ec, 576, 1920);
        dim3 g1g((2 * ec + 63) / 64, 8);
        k_gemm<<<g1g, 256, 0, stream>>>(mp, 7296, 1920, 1536, 2,
                                        wm1, (const float*)nullptr, 0, y1, 512, 2 * ec, 512, 1536);
        dim3 g2g((2 * ec + 63) / 64, 6);
        k_gemm<<<g2g, 256, 0, stream>>>(mp, 7296, 4992, 1152, 2,
                                        wm2, (const float*)nullptr, 0, y2, 384, 2 * ec, 384, 1152);

        k_combine<<<dim3(ec), 256, 0, stream>>>(wgn, y0, y1, y2, pwT, pb, out, e0);
    }
}

// Round 2
// 1524.458 us; speedup vs baseline: 2.6299x; 2.6299x over previous
//
#include <hip/hip_runtime.h>
#include <hip/hip_bf16.h>
#include <stdint.h>

// Problem constants
//  L=4, MM=2, C=128, H=64, OUTC=128, EDGE_CH=128, X_EDGE=384, C3=384
//  NRED=19, NFULL=25, E=10000
//  Effective w_m0 rows 512..1087 (576 outs, padded to 640)

__constant__ int c_MASKP[19] = {0,2,6,12,20, 3,7,13,21, 1,5,11,19, 8,14,22, 4,10,18};
__constant__ int c_GATEP[19] = {-1,0,1,2,3, 0,1,2,3, 0,1,2,3, 1,2,3, 1,2,3};
__constant__ int c_LFULL[25] = {0,1,1,1,2,2,2,2,2,3,3,3,3,3,3,3,4,4,4,4,4,4,4,4,4};

__device__ __forceinline__ float sigm_(float x) { return 1.f / (1.f + __expf(-x)); }

typedef __attribute__((ext_vector_type(8))) __bf16 bf16x8;
typedef __attribute__((ext_vector_type(4))) float floatx4;

__device__ __forceinline__ void async16(const void* g, void* l) {
    __builtin_amdgcn_global_load_lds(
        (__attribute__((address_space(1))) void*)(g),
        (__attribute__((address_space(3))) void*)(l), 16, 0, 0);
}

// ---------------------------------------------------------------------------
// K0: transpose proj_w (5,128,64) -> pwT (5,64,128)
__global__ void k_transpose_pw(const float* __restrict__ pw, float* __restrict__ pwT) {
    int d = blockIdx.x * 256 + threadIdx.x;
    if (d >= 40960) return;
    int l = d >> 13, rem = d & 8191, i = rem >> 7, o = rem & 127;
    pwT[d] = pw[(l << 13) + o * 64 + i];
}

// ---------------------------------------------------------------------------
// Kc: fp32 weight [rows][K] -> bf16 [rowsPad][K], pad rows zero
__global__ void k_cvt_w(const float* __restrict__ W, __hip_bfloat16* __restrict__ out,
                        int rows, int rowsPad, int K) {
    long i = (long)blockIdx.x * 256 + threadIdx.x;
    if (i >= (long)rowsPad * K) return;
    int r = (int)(i / K);
    out[i] = __float2bfloat16(r < rows ? W[i] : 0.f);
}

// ---------------------------------------------------------------------------
// K1: radial MLP front: x_edge -> silu(LN(.@w1^T)) -> silu(LN(.@w2^T)) -> bf16
__global__ __launch_bounds__(256) void k_radial_front(
    const float* __restrict__ ed, const float* __restrict__ se, const float* __restrict__ te,
    const float* __restrict__ w1, const float* __restrict__ b1,
    const float* __restrict__ g1, const float* __restrict__ bb1,
    const float* __restrict__ w2, const float* __restrict__ b2,
    const float* __restrict__ g2, const float* __restrict__ bb2,
    const int* __restrict__ an, const int* __restrict__ eidx,
    __hip_bfloat16* __restrict__ h2out, int e0, int ec, int E)
{
    __shared__ float xe[8 * 384];
    __shared__ float hb[8 * 128];
    __shared__ float hb2[8 * 128];
    __shared__ float stats[8][2];
    int tid = threadIdx.x;
    int ebase = e0 + blockIdx.x * 8;
    int elim = e0 + ec;

    for (int idx = tid; idx < 8 * 384; idx += 256) {
        int es = idx / 384, c = idx - es * 384;
        int e = ebase + es;
        float v = 0.f;
        if (e < elim) {
            if (c < 128)       v = ed[(long)e * 128 + c];
            else if (c < 256)  { int s = eidx[e];     v = se[an[s] * 128 + (c - 128)]; }
            else               { int t = eidx[E + e]; v = te[an[t] * 128 + (c - 256)]; }
        }
        xe[idx] = v;
    }
    __syncthreads();

    int o = tid & 127;
    int half = tid >> 7;
    for (int pass = 0; pass < 4; ++pass) {
        int es = pass * 2 + half;
        float acc = b1[o];
        const float4* wr = (const float4*)(w1 + (long)o * 384);
        const float4* xr = (const float4*)(xe + es * 384);
        #pragma unroll 8
        for (int k = 0; k < 96; ++k) {
            float4 w = wr[k], xv = xr[k];
            acc += w.x * xv.x + w.y * xv.y + w.z * xv.z + w.w * xv.w;
        }
        hb[es * 128 + o] = acc;
    }
    __syncthreads();
    if (tid < 8) {
        float s = 0.f, s2 = 0.f;
        for (int k = 0; k < 128; ++k) { float v = hb[tid * 128 + k]; s += v; s2 += v * v; }
        float mu = s * (1.f / 128.f);
        float var = s2 * (1.f / 128.f) - mu * mu;
        stats[tid][0] = mu;
        stats[tid][1] = rsqrtf(var + 1e-5f);
    }
    __syncthreads();
    for (int idx = tid; idx < 1024; idx += 256) {
        int es = idx >> 7, c = idx & 127;
        float v = (hb[idx] - stats[es][0]) * stats[es][1] * g1[c] + bb1[c];
        hb[idx] = v * sigm_(v);
    }
    __syncthreads();
    for (int pass = 0; pass < 4; ++pass) {
        int es = pass * 2 + half;
        float acc = b2[o];
        const float4* wr = (const float4*)(w2 + (long)o * 128);
        const float4* xr = (const float4*)(hb + es * 128);
        #pragma unroll 8
        for (int k = 0; k < 32; ++k) {
            float4 w = wr[k], xv = xr[k];
            acc += w.x * xv.x + w.y * xv.y + w.z * xv.z + w.w * xv.w;
        }
        hb2[es * 128 + o] = acc;
    }
    __syncthreads();
    if (tid < 8) {
        float s = 0.f, s2 = 0.f;
        for (int k = 0; k < 128; ++k) { float v = hb2[tid * 128 + k]; s += v; s2 += v * v; }
        float mu = s * (1.f / 128.f);
        float var = s2 * (1.f / 128.f) - mu * mu;
        stats[tid][0] = mu;
        stats[tid][1] = rsqrtf(var + 1e-5f);
    }
    __syncthreads();
    for (int idx = tid; idx < 1024; idx += 256) {
        int es = idx >> 7, c = idx & 127;
        int e = ebase + es;
        if (e < elim) {
            float v = (hb2[idx] - stats[es][0]) * stats[es][1] * g2[c] + bb2[c];
            v = v * sigm_(v);
            h2out[(long)(e - e0) * 128 + c] = __float2bfloat16(v);
        }
    }
}

// ---------------------------------------------------------------------------
// MFMA GEMM (m97 structure): Out[r][o] = sum_k A[r][k]*B[o][k] (+bias[o])
// A: bf16 [Mpad][K], B: bf16 [Npad][K]; grid (Mpad/128, Npad/128); 256 thr.
__global__ __launch_bounds__(256) void k_mfma_gemm(
    const __hip_bfloat16* __restrict__ A,
    const __hip_bfloat16* __restrict__ B,
    const float* __restrict__ bias,
    float* __restrict__ Out, int ldo,
    int realM, int realN, int K)
{
    __shared__ __align__(16) __hip_bfloat16 As[128 * 32];
    __shared__ __align__(16) __hip_bfloat16 Bs[128 * 32];
    int tid = threadIdx.x;
    int l = tid & 63, w = tid >> 6;
    int r0 = blockIdx.x * 128, n0 = blockIdx.y * 128;
    int wm = w & 1, wn = w >> 1;

    floatx4 acc[4][4] = {};

    // staging addresses: wave w covers rows [w*16, w*16+16) (op0) and +64 (op1)
    int srow = w * 16 + (l >> 2);
    int scol = (l & 3) * 8;
    const __hip_bfloat16* Ag = A + (long)(r0 + srow) * K + scol;
    const __hip_bfloat16* Bg = B + (long)(n0 + srow) * K + scol;
    __hip_bfloat16* AsW = As + (w * 16) * 32;   // + lane*8 elements implicit
    __hip_bfloat16* BsW = Bs + (w * 16) * 32;

    int lrow = l & 15, lk = (l >> 4) * 8;

    for (int kk = 0; kk < K; kk += 32) {
        async16(Ag + kk, AsW);
        async16(Ag + (long)64 * K + kk, AsW + 64 * 32);
        async16(Bg + kk, BsW);
        async16(Bg + (long)64 * K + kk, BsW + 64 * 32);
        __syncthreads();
        bf16x8 af[4], bf[4];
        #pragma unroll
        for (int mi = 0; mi < 4; ++mi)
            af[mi] = *(const bf16x8*)&As[(wm * 64 + mi * 16 + lrow) * 32 + lk];
        #pragma unroll
        for (int ni = 0; ni < 4; ++ni)
            bf[ni] = *(const bf16x8*)&Bs[(wn * 64 + ni * 16 + lrow) * 32 + lk];
        #pragma unroll
        for (int mi = 0; mi < 4; ++mi)
            #pragma unroll
            for (int ni = 0; ni < 4; ++ni)
                acc[mi][ni] = __builtin_amdgcn_mfma_f32_16x16x32_bf16(
                    af[mi], bf[ni], acc[mi][ni], 0, 0, 0);
        __syncthreads();
    }

    int lq = l >> 4;
    #pragma unroll
    for (int ni = 0; ni < 4; ++ni) {
        int col = n0 + wn * 64 + ni * 16 + lrow;
        if (col >= realN) continue;
        float bv = bias ? bias[col] : 0.f;
        #pragma unroll
        for (int mi = 0; mi < 4; ++mi) {
            int rbase = r0 + wm * 64 + mi * 16 + lq * 4;
            floatx4 v = acc[mi][ni];
            #pragma unroll
            for (int r = 0; r < 4; ++r) {
                int row = rbase + r;
                if (row < realM) Out[(long)row * ldo + col] = v[r] + bv;
            }
        }
    }
}

// ---------------------------------------------------------------------------
// K3: per edge: gather+scale msg, Wigner-contract, scatter bf16 into A0/A1/A2
__global__ __launch_bounds__(384) void k_build_mp(
    const float* __restrict__ x, const float* __restrict__ ef, const float* __restrict__ wgn,
    const float* __restrict__ wrad, const int* __restrict__ eidx,
    __hip_bfloat16* __restrict__ A0, __hip_bfloat16* __restrict__ A1,
    __hip_bfloat16* __restrict__ A2, int e0, int E)
{
    __shared__ float swig[625];
    __shared__ float srad[1920];
    __shared__ float smsg[9600];
    int tid = threadIdx.x;
    int le = blockIdx.x;
    long e = e0 + le;
    int src = eidx[e], tgt = eidx[E + e];

    for (int i = tid; i < 625; i += 384)  swig[i] = wgn[e * 625 + i];
    for (int i = tid; i < 1920; i += 384) srad[i] = wrad[(long)le * 1920 + i];
    __syncthreads();
    int c = tid;  // 0..383
    for (int n = 0; n < 25; ++n) {
        float v;
        if (c < 128)      v = x[(long)src * 3200 + n * 128 + c];
        else if (c < 256) v = x[(long)tgt * 3200 + n * 128 + (c - 128)];
        else              v = ef[e * 3200 + n * 128 + (c - 256)];
        smsg[n * 384 + c] = v * srad[c_LFULL[n] * 384 + c];
    }
    __syncthreads();
    for (int j = 0; j < 19; ++j) {
        const float* wrow = swig + c_MASKP[j] * 25;
        float acc = 0.f;
        #pragma unroll
        for (int n = 0; n < 25; ++n) acc += wrow[n] * smsg[n * 384 + c];
        __hip_bfloat16 hv = __float2bfloat16(acc);
        if (j < 5)       A0[(long)le * 1920 + j * 384 + c] = hv;
        else if (j < 9)  A1[(long)(2 * le)     * 1536 + (j - 5)  * 384 + c] = hv;
        else if (j < 13) A1[(long)(2 * le + 1) * 1536 + (j - 9)  * 384 + c] = hv;
        else if (j < 16) A2[(long)(2 * le)     * 1152 + (j - 13) * 384 + c] = hv;
        else             A2[(long)(2 * le + 1) * 1152 + (j - 16) * 384 + c] = hv;
    }
}

// ---------------------------------------------------------------------------
// K5: recombine + gate + transposed Wigner + projection
__global__ __launch_bounds__(256) void k_combine(
    const float* __restrict__ wgn, const float* __restrict__ ym0,
    const float* __restrict__ ym1, const float* __restrict__ ym2,
    const float* __restrict__ pwT, const float* __restrict__ pb,
    float* __restrict__ out, int e0)
{
    __shared__ float swig[625];
    __shared__ float shl[1216];   // 19 x 64
    __shared__ float sful[1600];  // 25 x 64
    __shared__ float spw[8192];   // 64 x 128 (one l at a time)
    int tid = threadIdx.x;
    int le = blockIdx.x;
    long e = e0 + le;

    for (int i = tid; i < 625; i += 256) swig[i] = wgn[e * 625 + i];

    const float* y0  = ym0 + (long)le * 576;
    const float* y1a = ym1 + (long)(2 * le) * 512;
    const float* y1b = ym1 + (long)(2 * le + 1) * 512;
    const float* y2a = ym2 + (long)(2 * le) * 384;
    const float* y2b = ym2 + (long)(2 * le + 1) * 384;

    for (int i = tid; i < 1216; i += 256) {
        int j = i >> 6, c = i & 63;
        float raw;
        if (j < 5)        raw = y0[256 + j * 64 + c];
        else if (j < 9)   { int k = (j - 5) * 64 + c;  raw = y1a[k] - y1b[256 + k]; }
        else if (j < 13)  { int k = (j - 9) * 64 + c;  raw = y1b[k] + y1a[256 + k]; }
        else if (j < 16)  { int k = (j - 13) * 64 + c; raw = y2a[k] - y2b[192 + k]; }
        else              { int k = (j - 16) * 64 + c; raw = y2b[k] + y2a[192 + k]; }
        float v;
        if (j == 0) v = raw * sigm_(raw);
        else        v = raw * sigm_(y0[c_GATEP[j] * 64 + c]);
        shl[i] = v;
    }
    __syncthreads();
    for (int i = tid; i < 1600; i += 256) {
        int n = i >> 6, c = i & 63;
        float acc = 0.f;
        #pragma unroll
        for (int j = 0; j < 19; ++j) acc += swig[c_MASKP[j] * 25 + n] * shl[j * 64 + c];
        sful[i] = acc;
    }

    int o = tid & 127, sub = tid >> 7;
    for (int l = 0; l < 5; ++l) {
        __syncthreads();
        for (int i = tid; i < 8192; i += 256) spw[i] = pwT[l * 8192 + i];
        __syncthreads();
        int cnt = 2 * l + 1, nb = l * l;
        for (int ni = sub; ni < cnt; ni += 2) {
            int n = nb + ni;
            float acc = (n == 0) ? pb[o] : 0.f;
            const float* f = sful + n * 64;
            #pragma unroll 16
            for (int i = 0; i < 64; ++i) acc += f[i] * spw[i * 128 + o];
            out[e * 3200 + n * 128 + o] = acc;
        }
    }
}

// ---------------------------------------------------------------------------
extern "C" void kernel_launch(void* const* d_in, const int* in_sizes, int n_in,
                              void* d_out, int out_size, void* d_ws, size_t ws_size,
                              hipStream_t stream)
{
    const float* x    = (const float*)d_in[0];
    const float* ef   = (const float*)d_in[1];
    const float* ed   = (const float*)d_in[2];
    const float* wgn  = (const float*)d_in[3];
    const float* se   = (const float*)d_in[4];
    const float* te   = (const float*)d_in[5];
    const float* w1   = (const float*)d_in[6];
    const float* b1   = (const float*)d_in[7];
    const float* g1   = (const float*)d_in[8];
    const float* bb1  = (const float*)d_in[9];
    const float* w2   = (const float*)d_in[10];
    const float* b2   = (const float*)d_in[11];
    const float* g2   = (const float*)d_in[12];
    const float* bb2  = (const float*)d_in[13];
    const float* w3   = (const float*)d_in[14];
    const float* b3   = (const float*)d_in[15];
    const float* wm0  = (const float*)d_in[16];
    const float* bm0  = (const float*)d_in[17];
    const float* wm1  = (const float*)d_in[18];
    const float* wm2  = (const float*)d_in[19];
    const float* pw   = (const float*)d_in[20];
    const float* pb   = (const float*)d_in[21];
    const int*   an   = (const int*)d_in[22];
    const int*   eidx = (const int*)d_in[23];
    float* out = (float*)d_out;
    char*  ws  = (char*)d_ws;

    const int E = in_sizes[23] / 2;           // 10000

    // fixed-region layout (all sizes multiples of 256 B)
    size_t off = 0;
    float* pwT = (float*)(ws + off); off += 163840;                    // 40960 f32
    __hip_bfloat16* Wb0 = (__hip_bfloat16*)(ws + off); off += 640L  * 1920 * 2;
    __hip_bfloat16* Wb1 = (__hip_bfloat16*)(ws + off); off += 512L  * 1536 * 2;
    __hip_bfloat16* Wb2 = (__hip_bfloat16*)(ws + off); off += 384L  * 1152 * 2;
    __hip_bfloat16* Wb3 = (__hip_bfloat16*)(ws + off); off += 1920L * 128  * 2;
    size_t fixedBytes = off;

    // per-edge bytes: h2b 256 + wrad 7680 + A0 3840 + A1 6144 + A2 4608
    //               + y0 2304 + y1 4096 + y2 3072 = 32000
    long usable = (long)ws_size - (long)fixedBytes;
    long ceRaw = usable / 32000;
    long Epad = ((long)E + 127) & ~127L;
    long CE = ceRaw & ~127L;            // multiple of 128
    if (CE > Epad) CE = Epad;
    if (CE < 128) CE = 128;

    __hip_bfloat16* h2b = (__hip_bfloat16*)(ws + off); off += CE * 128 * 2;
    float* wrad = (float*)(ws + off);                  off += CE * 1920 * 4;
    __hip_bfloat16* A0 = (__hip_bfloat16*)(ws + off);  off += CE * 1920 * 2;
    __hip_bfloat16* A1 = (__hip_bfloat16*)(ws + off);  off += 2 * CE * 1536 * 2;
    __hip_bfloat16* A2 = (__hip_bfloat16*)(ws + off);  off += 2 * CE * 1152 * 2;
    float* y0 = (float*)(ws + off);                    off += CE * 576 * 4;
    float* y1 = (float*)(ws + off);                    off += 2 * CE * 512 * 4;
    float* y2 = (float*)(ws + off);                    off += 2 * CE * 384 * 4;

    k_transpose_pw<<<160, 256, 0, stream>>>(pw, pwT);
    k_cvt_w<<<(640 * 1920 + 255) / 256, 256, 0, stream>>>(wm0 + 512L * 1920, Wb0, 576, 640, 1920);
    k_cvt_w<<<(512 * 1536 + 255) / 256, 256, 0, stream>>>(wm1, Wb1, 512, 512, 1536);
    k_cvt_w<<<(384 * 1152 + 255) / 256, 256, 0, stream>>>(wm2, Wb2, 384, 384, 1152);
    k_cvt_w<<<(1920 * 128 + 255) / 256, 256, 0, stream>>>(w3, Wb3, 1920, 1920, 128);

    for (int e0 = 0; e0 < E; e0 += (int)CE) {
        int ec = (E - e0 < (int)CE) ? (E - e0) : (int)CE;
        int Mp  = (ec + 127) & ~127;        // padded rows for A0/h2b GEMMs
        int Mp2 = (2 * ec + 127) & ~127;    // padded rows for A1/A2 GEMMs

        k_radial_front<<<dim3((ec + 7) / 8), 256, 0, stream>>>(
            ed, se, te, w1, b1, g1, bb1, w2, b2, g2, bb2, an, eidx, h2b, e0, ec, E);

        // wrad = h2 @ w3^T + b3   (M=ec, N=1920, K=128)
        k_mfma_gemm<<<dim3(Mp / 128, 1920 / 128), 256, 0, stream>>>(
            h2b, Wb3, b3, wrad, 1920, ec, 1920, 128);

        k_build_mp<<<dim3(ec), 384, 0, stream>>>(x, ef, wgn, wrad, eidx, A0, A1, A2, e0, E);

        // y0 = A0 @ Wb0^T + bm0[512:]   (M=ec, N=576 (pad 640), K=1920)
        k_mfma_gemm<<<dim3(Mp / 128, 640 / 128), 256, 0, stream>>>(
            A0, Wb0, bm0 + 512, y0, 576, ec, 576, 1920);
        // y1 = A1 @ Wb1^T               (M=2ec, N=512, K=1536)
        k_mfma_gemm<<<dim3(Mp2 / 128, 512 / 128), 256, 0, stream>>>(
            A1, Wb1, (const float*)nullptr, y1, 512, 2 * ec, 512, 1536);
        // y2 = A2 @ Wb2^T               (M=2ec, N=384, K=1152)
        k_mfma_gemm<<<dim3(Mp2 / 128, 384 / 128), 256, 0, stream>>>(
            A2, Wb2, (const float*)nullptr, y2, 384, 2 * ec, 384, 1152);

        k_combine<<<dim3(ec), 256, 0, stream>>>(wgn, y0, y1, y2, pwT, pb, out, e0);
    }
}

// Round 3
// 1257.814 us; speedup vs baseline: 3.1874x; 1.2120x over previous
//
#include <hip/hip_runtime.h>
#include <hip/hip_bf16.h>
#include <stdint.h>

// Problem constants
//  L=4, MM=2, C=128, H=64, OUTC=128, EDGE_CH=128, X_EDGE=384, C3=384
//  NRED=19, NFULL=25, E=10000
//  Effective w_m0 rows 512..1087 (576 outs, padded to 640)

__constant__ int c_MASKP[19] = {0,2,6,12,20, 3,7,13,21, 1,5,11,19, 8,14,22, 4,10,18};
__constant__ int c_GATEP[19] = {-1,0,1,2,3, 0,1,2,3, 0,1,2,3, 1,2,3, 1,2,3};
__constant__ int c_LFULL[25] = {0,1,1,1,2,2,2,2,2,3,3,3,3,3,3,3,4,4,4,4,4,4,4,4,4};

__device__ __forceinline__ float sigm_(float x) { return 1.f / (1.f + __expf(-x)); }

typedef __attribute__((ext_vector_type(8))) __bf16 bf16x8;
typedef __attribute__((ext_vector_type(4))) float floatx4;

__device__ __forceinline__ void async16(const void* g, void* l) {
    __builtin_amdgcn_global_load_lds(
        (__attribute__((address_space(1))) void*)(g),
        (__attribute__((address_space(3))) void*)(l), 16, 0, 0);
}

// ---------------------------------------------------------------------------
// K0: transpose proj_w (5,128,64) -> pwT (5,64,128)
__global__ void k_transpose_pw(const float* __restrict__ pw, float* __restrict__ pwT) {
    int d = blockIdx.x * 256 + threadIdx.x;
    if (d >= 40960) return;
    int l = d >> 13, rem = d & 8191, i = rem >> 7, o = rem & 127;
    pwT[d] = pw[(l << 13) + o * 64 + i];
}

// ---------------------------------------------------------------------------
// Kc: fp32 weight [rows][K] -> bf16 [rowsPad][K], pad rows zero
__global__ void k_cvt_w(const float* __restrict__ W, __hip_bfloat16* __restrict__ out,
                        int rows, int rowsPad, int K) {
    long i = (long)blockIdx.x * 256 + threadIdx.x;
    if (i >= (long)rowsPad * K) return;
    int r = (int)(i / K);
    out[i] = __float2bfloat16(r < rows ? W[i] : 0.f);
}

// ---------------------------------------------------------------------------
// K1: radial MLP front: x_edge -> silu(LN(.@w1^T)) -> silu(LN(.@w2^T)) -> bf16
__global__ __launch_bounds__(256) void k_radial_front(
    const float* __restrict__ ed, const float* __restrict__ se, const float* __restrict__ te,
    const float* __restrict__ w1, const float* __restrict__ b1,
    const float* __restrict__ g1, const float* __restrict__ bb1,
    const float* __restrict__ w2, const float* __restrict__ b2,
    const float* __restrict__ g2, const float* __restrict__ bb2,
    const int* __restrict__ an, const int* __restrict__ eidx,
    __hip_bfloat16* __restrict__ h2out, int e0, int ec, int E)
{
    __shared__ float xe[8 * 384];
    __shared__ float hb[8 * 128];
    __shared__ float hb2[8 * 128];
    __shared__ float stats[8][2];
    int tid = threadIdx.x;
    int ebase = e0 + blockIdx.x * 8;
    int elim = e0 + ec;

    for (int idx = tid; idx < 8 * 384; idx += 256) {
        int es = idx / 384, c = idx - es * 384;
        int e = ebase + es;
        float v = 0.f;
        if (e < elim) {
            if (c < 128)       v = ed[(long)e * 128 + c];
            else if (c < 256)  { int s = eidx[e];     v = se[an[s] * 128 + (c - 128)]; }
            else               { int t = eidx[E + e]; v = te[an[t] * 128 + (c - 256)]; }
        }
        xe[idx] = v;
    }
    __syncthreads();

    int o = tid & 127;
    int half = tid >> 7;
    for (int pass = 0; pass < 4; ++pass) {
        int es = pass * 2 + half;
        float acc = b1[o];
        const float4* wr = (const float4*)(w1 + (long)o * 384);
        const float4* xr = (const float4*)(xe + es * 384);
        #pragma unroll 8
        for (int k = 0; k < 96; ++k) {
            float4 w = wr[k], xv = xr[k];
            acc += w.x * xv.x + w.y * xv.y + w.z * xv.z + w.w * xv.w;
        }
        hb[es * 128 + o] = acc;
    }
    __syncthreads();
    if (tid < 8) {
        float s = 0.f, s2 = 0.f;
        for (int k = 0; k < 128; ++k) { float v = hb[tid * 128 + k]; s += v; s2 += v * v; }
        float mu = s * (1.f / 128.f);
        float var = s2 * (1.f / 128.f) - mu * mu;
        stats[tid][0] = mu;
        stats[tid][1] = rsqrtf(var + 1e-5f);
    }
    __syncthreads();
    for (int idx = tid; idx < 1024; idx += 256) {
        int es = idx >> 7, c = idx & 127;
        float v = (hb[idx] - stats[es][0]) * stats[es][1] * g1[c] + bb1[c];
        hb[idx] = v * sigm_(v);
    }
    __syncthreads();
    for (int pass = 0; pass < 4; ++pass) {
        int es = pass * 2 + half;
        float acc = b2[o];
        const float4* wr = (const float4*)(w2 + (long)o * 128);
        const float4* xr = (const float4*)(hb + es * 128);
        #pragma unroll 8
        for (int k = 0; k < 32; ++k) {
            float4 w = wr[k], xv = xr[k];
            acc += w.x * xv.x + w.y * xv.y + w.z * xv.z + w.w * xv.w;
        }
        hb2[es * 128 + o] = acc;
    }
    __syncthreads();
    if (tid < 8) {
        float s = 0.f, s2 = 0.f;
        for (int k = 0; k < 128; ++k) { float v = hb2[tid * 128 + k]; s += v; s2 += v * v; }
        float mu = s * (1.f / 128.f);
        float var = s2 * (1.f / 128.f) - mu * mu;
        stats[tid][0] = mu;
        stats[tid][1] = rsqrtf(var + 1e-5f);
    }
    __syncthreads();
    for (int idx = tid; idx < 1024; idx += 256) {
        int es = idx >> 7, c = idx & 127;
        int e = ebase + es;
        if (e < elim) {
            float v = (hb2[idx] - stats[es][0]) * stats[es][1] * g2[c] + bb2[c];
            v = v * sigm_(v);
            h2out[(long)(e - e0) * 128 + c] = __float2bfloat16(v);
        }
    }
}

// ---------------------------------------------------------------------------
// MFMA GEMM (m97 structure): Out[r][o] = sum_k A[r][k]*B[o][k] (+bias[o])
// A: bf16 [Mpad][K], B: bf16 [Npad][K]; grid (Mpad/128, Npad/128); 256 thr.
__global__ __launch_bounds__(256) void k_mfma_gemm(
    const __hip_bfloat16* __restrict__ A,
    const __hip_bfloat16* __restrict__ B,
    const float* __restrict__ bias,
    float* __restrict__ Out, int ldo,
    int realM, int realN, int K)
{
    __shared__ __align__(16) __hip_bfloat16 As[128 * 32];
    __shared__ __align__(16) __hip_bfloat16 Bs[128 * 32];
    int tid = threadIdx.x;
    int l = tid & 63, w = tid >> 6;
    int r0 = blockIdx.x * 128, n0 = blockIdx.y * 128;
    int wm = w & 1, wn = w >> 1;

    floatx4 acc[4][4] = {};

    int srow = w * 16 + (l >> 2);
    int scol = (l & 3) * 8;
    const __hip_bfloat16* Ag = A + (long)(r0 + srow) * K + scol;
    const __hip_bfloat16* Bg = B + (long)(n0 + srow) * K + scol;
    __hip_bfloat16* AsW = As + (w * 16) * 32;
    __hip_bfloat16* BsW = Bs + (w * 16) * 32;

    int lrow = l & 15, lk = (l >> 4) * 8;

    for (int kk = 0; kk < K; kk += 32) {
        async16(Ag + kk, AsW);
        async16(Ag + (long)64 * K + kk, AsW + 64 * 32);
        async16(Bg + kk, BsW);
        async16(Bg + (long)64 * K + kk, BsW + 64 * 32);
        __syncthreads();
        bf16x8 af[4], bf[4];
        #pragma unroll
        for (int mi = 0; mi < 4; ++mi)
            af[mi] = *(const bf16x8*)&As[(wm * 64 + mi * 16 + lrow) * 32 + lk];
        #pragma unroll
        for (int ni = 0; ni < 4; ++ni)
            bf[ni] = *(const bf16x8*)&Bs[(wn * 64 + ni * 16 + lrow) * 32 + lk];
        #pragma unroll
        for (int mi = 0; mi < 4; ++mi)
            #pragma unroll
            for (int ni = 0; ni < 4; ++ni)
                acc[mi][ni] = __builtin_amdgcn_mfma_f32_16x16x32_bf16(
                    af[mi], bf[ni], acc[mi][ni], 0, 0, 0);
        __syncthreads();
    }

    int lq = l >> 4;
    #pragma unroll
    for (int ni = 0; ni < 4; ++ni) {
        int col = n0 + wn * 64 + ni * 16 + lrow;
        if (col >= realN) continue;
        float bv = bias ? bias[col] : 0.f;
        #pragma unroll
        for (int mi = 0; mi < 4; ++mi) {
            int rbase = r0 + wm * 64 + mi * 16 + lq * 4;
            floatx4 v = acc[mi][ni];
            #pragma unroll
            for (int r = 0; r < 4; ++r) {
                int row = rbase + r;
                if (row < realM) Out[(long)row * ldo + col] = v[r] + bv;
            }
        }
    }
}

// ---------------------------------------------------------------------------
// K3 (register version): per edge, thread c streams n=0..24:
//   one coalesced global load, scale by reg-held rad[l], accumulate 19
//   register accs with broadcast LDS reads of pre-permuted Wigner rows.
// No smsg/srad LDS; ~1.9 KB LDS/block.
__global__ __launch_bounds__(384) void k_build_mp(
    const float* __restrict__ x, const float* __restrict__ ef, const float* __restrict__ wgn,
    const float* __restrict__ wrad, const int* __restrict__ eidx,
    __hip_bfloat16* __restrict__ A0, __hip_bfloat16* __restrict__ A1,
    __hip_bfloat16* __restrict__ A2, int e0, int E)
{
    __shared__ float swig[475];   // 19 permuted rows x 25
    int tid = threadIdx.x;
    int le = blockIdx.x;
    long e = e0 + le;
    int src = eidx[e], tgt = eidx[E + e];

    for (int i = tid; i < 475; i += 384) {
        int j = i / 25, n = i - j * 25;
        swig[i] = wgn[e * 625 + c_MASKP[j] * 25 + n];
    }

    int c = tid;  // 0..383 (wave-uniform branch: waves 0-1 src, 2-3 tgt, 4-5 ef)
    float rad[5];
    #pragma unroll
    for (int l = 0; l < 5; ++l) rad[l] = wrad[(long)le * 1920 + l * 384 + c];

    const float* base;
    if (c < 128)      base = x  + (long)src * 3200 + c;
    else if (c < 256) base = x  + (long)tgt * 3200 + (c - 128);
    else              base = ef + e * 3200 + (c - 256);

    __syncthreads();

    float acc[19] = {};
    #pragma unroll
    for (int n = 0; n < 25; ++n) {
        float v = base[n * 128] * rad[c_LFULL[n]];
        #pragma unroll
        for (int j = 0; j < 19; ++j)
            acc[j] += swig[j * 25 + n] * v;
    }

    #pragma unroll
    for (int j = 0; j < 19; ++j) {
        __hip_bfloat16 hv = __float2bfloat16(acc[j]);
        if (j < 5)       A0[(long)le * 1920 + j * 384 + c] = hv;
        else if (j < 9)  A1[(long)(2 * le)     * 1536 + (j - 5)  * 384 + c] = hv;
        else if (j < 13) A1[(long)(2 * le + 1) * 1536 + (j - 9)  * 384 + c] = hv;
        else if (j < 16) A2[(long)(2 * le)     * 1152 + (j - 13) * 384 + c] = hv;
        else             A2[(long)(2 * le + 1) * 1152 + (j - 16) * 384 + c] = hv;
    }
}

// ---------------------------------------------------------------------------
// K5: recombine + gate + transposed Wigner + projection
__global__ __launch_bounds__(256) void k_combine(
    const float* __restrict__ wgn, const float* __restrict__ ym0,
    const float* __restrict__ ym1, const float* __restrict__ ym2,
    const float* __restrict__ pwT, const float* __restrict__ pb,
    float* __restrict__ out, int e0)
{
    __shared__ float swig[625];
    __shared__ float shl[1216];   // 19 x 64
    __shared__ float sful[1600];  // 25 x 64
    __shared__ float spw[8192];   // 64 x 128 (one l at a time)
    int tid = threadIdx.x;
    int le = blockIdx.x;
    long e = e0 + le;

    for (int i = tid; i < 625; i += 256) swig[i] = wgn[e * 625 + i];

    const float* y0  = ym0 + (long)le * 576;
    const float* y1a = ym1 + (long)(2 * le) * 512;
    const float* y1b = ym1 + (long)(2 * le + 1) * 512;
    const float* y2a = ym2 + (long)(2 * le) * 384;
    const float* y2b = ym2 + (long)(2 * le + 1) * 384;

    for (int i = tid; i < 1216; i += 256) {
        int j = i >> 6, c = i & 63;
        float raw;
        if (j < 5)        raw = y0[256 + j * 64 + c];
        else if (j < 9)   { int k = (j - 5) * 64 + c;  raw = y1a[k] - y1b[256 + k]; }
        else if (j < 13)  { int k = (j - 9) * 64 + c;  raw = y1b[k] + y1a[256 + k]; }
        else if (j < 16)  { int k = (j - 13) * 64 + c; raw = y2a[k] - y2b[192 + k]; }
        else              { int k = (j - 16) * 64 + c; raw = y2b[k] + y2a[192 + k]; }
        float v;
        if (j == 0) v = raw * sigm_(raw);
        else        v = raw * sigm_(y0[c_GATEP[j] * 64 + c]);
        shl[i] = v;
    }
    __syncthreads();
    for (int i = tid; i < 1600; i += 256) {
        int n = i >> 6, c = i & 63;
        float acc = 0.f;
        #pragma unroll
        for (int j = 0; j < 19; ++j) acc += swig[c_MASKP[j] * 25 + n] * shl[j * 64 + c];
        sful[i] = acc;
    }

    int o = tid & 127, sub = tid >> 7;
    for (int l = 0; l < 5; ++l) {
        __syncthreads();
        for (int i = tid; i < 8192; i += 256) spw[i] = pwT[l * 8192 + i];
        __syncthreads();
        int cnt = 2 * l + 1, nb = l * l;
        for (int ni = sub; ni < cnt; ni += 2) {
            int n = nb + ni;
            float acc = (n == 0) ? pb[o] : 0.f;
            const float* f = sful + n * 64;
            #pragma unroll 16
            for (int i = 0; i < 64; ++i) acc += f[i] * spw[i * 128 + o];
            out[e * 3200 + n * 128 + o] = acc;
        }
    }
}

// ---------------------------------------------------------------------------
extern "C" void kernel_launch(void* const* d_in, const int* in_sizes, int n_in,
                              void* d_out, int out_size, void* d_ws, size_t ws_size,
                              hipStream_t stream)
{
    const float* x    = (const float*)d_in[0];
    const float* ef   = (const float*)d_in[1];
    const float* ed   = (const float*)d_in[2];
    const float* wgn  = (const float*)d_in[3];
    const float* se   = (const float*)d_in[4];
    const float* te   = (const float*)d_in[5];
    const float* w1   = (const float*)d_in[6];
    const float* b1   = (const float*)d_in[7];
    const float* g1   = (const float*)d_in[8];
    const float* bb1  = (const float*)d_in[9];
    const float* w2   = (const float*)d_in[10];
    const float* b2   = (const float*)d_in[11];
    const float* g2   = (const float*)d_in[12];
    const float* bb2  = (const float*)d_in[13];
    const float* w3   = (const float*)d_in[14];
    const float* b3   = (const float*)d_in[15];
    const float* wm0  = (const float*)d_in[16];
    const float* bm0  = (const float*)d_in[17];
    const float* wm1  = (const float*)d_in[18];
    const float* wm2  = (const float*)d_in[19];
    const float* pw   = (const float*)d_in[20];
    const float* pb   = (const float*)d_in[21];
    const int*   an   = (const int*)d_in[22];
    const int*   eidx = (const int*)d_in[23];
    float* out = (float*)d_out;
    char*  ws  = (char*)d_ws;

    const int E = in_sizes[23] / 2;           // 10000

    size_t off = 0;
    float* pwT = (float*)(ws + off); off += 163840;
    __hip_bfloat16* Wb0 = (__hip_bfloat16*)(ws + off); off += 640L  * 1920 * 2;
    __hip_bfloat16* Wb1 = (__hip_bfloat16*)(ws + off); off += 512L  * 1536 * 2;
    __hip_bfloat16* Wb2 = (__hip_bfloat16*)(ws + off); off += 384L  * 1152 * 2;
    __hip_bfloat16* Wb3 = (__hip_bfloat16*)(ws + off); off += 1920L * 128  * 2;
    size_t fixedBytes = off;

    long usable = (long)ws_size - (long)fixedBytes;
    long ceRaw = usable / 32000;
    long Epad = ((long)E + 127) & ~127L;
    long CE = ceRaw & ~127L;
    if (CE > Epad) CE = Epad;
    if (CE < 128) CE = 128;

    __hip_bfloat16* h2b = (__hip_bfloat16*)(ws + off); off += CE * 128 * 2;
    float* wrad = (float*)(ws + off);                  off += CE * 1920 * 4;
    __hip_bfloat16* A0 = (__hip_bfloat16*)(ws + off);  off += CE * 1920 * 2;
    __hip_bfloat16* A1 = (__hip_bfloat16*)(ws + off);  off += 2 * CE * 1536 * 2;
    __hip_bfloat16* A2 = (__hip_bfloat16*)(ws + off);  off += 2 * CE * 1152 * 2;
    float* y0 = (float*)(ws + off);                    off += CE * 576 * 4;
    float* y1 = (float*)(ws + off);                    off += 2 * CE * 512 * 4;
    float* y2 = (float*)(ws + off);                    off += 2 * CE * 384 * 4;

    k_transpose_pw<<<160, 256, 0, stream>>>(pw, pwT);
    k_cvt_w<<<(640 * 1920 + 255) / 256, 256, 0, stream>>>(wm0 + 512L * 1920, Wb0, 576, 640, 1920);
    k_cvt_w<<<(512 * 1536 + 255) / 256, 256, 0, stream>>>(wm1, Wb1, 512, 512, 1536);
    k_cvt_w<<<(384 * 1152 + 255) / 256, 256, 0, stream>>>(wm2, Wb2, 384, 384, 1152);
    k_cvt_w<<<(1920 * 128 + 255) / 256, 256, 0, stream>>>(w3, Wb3, 1920, 1920, 128);

    for (int e0 = 0; e0 < E; e0 += (int)CE) {
        int ec = (E - e0 < (int)CE) ? (E - e0) : (int)CE;
        int Mp  = (ec + 127) & ~127;
        int Mp2 = (2 * ec + 127) & ~127;

        k_radial_front<<<dim3((ec + 7) / 8), 256, 0, stream>>>(
            ed, se, te, w1, b1, g1, bb1, w2, b2, g2, bb2, an, eidx, h2b, e0, ec, E);

        k_mfma_gemm<<<dim3(Mp / 128, 1920 / 128), 256, 0, stream>>>(
            h2b, Wb3, b3, wrad, 1920, ec, 1920, 128);

        k_build_mp<<<dim3(ec), 384, 0, stream>>>(x, ef, wgn, wrad, eidx, A0, A1, A2, e0, E);

        k_mfma_gemm<<<dim3(Mp / 128, 640 / 128), 256, 0, stream>>>(
            A0, Wb0, bm0 + 512, y0, 576, ec, 576, 1920);
        k_mfma_gemm<<<dim3(Mp2 / 128, 512 / 128), 256, 0, stream>>>(
            A1, Wb1, (const float*)nullptr, y1, 512, 2 * ec, 512, 1536);
        k_mfma_gemm<<<dim3(Mp2 / 128, 384 / 128), 256, 0, stream>>>(
            A2, Wb2, (const float*)nullptr, y2, 384, 2 * ec, 384, 1152);

        k_combine<<<dim3(ec), 256, 0, stream>>>(wgn, y0, y1, y2, pwT, pb, out, e0);
    }
}